// Round 5
// baseline (815.980 us; speedup 1.0000x reference)
//
#include <hip/hip_runtime.h>
#include <hip/hip_bf16.h>
#include <math.h>

#define N_NODES 50000
#define E0      800000
#define E_TOT   (E0 + N_NODES)

using bf16 = __hip_bfloat16;

static __device__ __forceinline__ float ldf(const float* p){ return *p; }
static __device__ __forceinline__ float ldf(const bf16*  p){ return __bfloat162float(*p); }
static __device__ __forceinline__ void  stf(float* p, float v){ *p = v; }
static __device__ __forceinline__ void  stf(bf16*  p, float v){ *p = __float2bfloat16(v); }

// ---------------- dtype autodetect (edges: int32 vs int64; floats: fp32 vs bf16) ----
// flag[0]=1 -> edges int32 ; flag[1]=1 -> float tensors are fp32
__global__ void k_detect(const int* __restrict__ ei, const unsigned* __restrict__ xu,
                         int* __restrict__ flag){
    __shared__ int e32, f32;
    if (threadIdx.x == 0){ e32 = 0; f32 = 0; }
    __syncthreads();
    if (ei[2 * threadIdx.x + 1] != 0) e32 = 1;   // int64 high words are 0
    if (threadIdx.x < 128){
        unsigned ex = (xu[threadIdx.x] >> 7) & 0xFF;  // bf16 exponent of low halfword
        if (ex < 100 || ex > 140) f32 = 1;            // fp32 mantissa bits look random
    }
    __syncthreads();
    if (threadIdx.x == 0){ flag[0] = e32; flag[1] = f32; }
}

// ---------------- weight conversion to fp32 scratch ----------------
static __device__ __forceinline__ float ldany(const void* p, int i, int isf32){
    return isf32 ? ((const float*)p)[i] : __bfloat162float(((const bf16*)p)[i]);
}

// vecf layout: b1 @0(128), bg @128(64), b3 @192(64), att_s @256(128), att_d @384(128)
__global__ void k_convert(const int* __restrict__ flag,
                          const void* W1, const void* Wg, const void* W3,
                          const void* b1, const void* bg, const void* b3,
                          const void* as_, const void* ad_,
                          float* __restrict__ W1f, float* __restrict__ Wgf,
                          float* __restrict__ W3f, float* __restrict__ vecf){
    int isf = flag[1];
    int b = blockIdx.x, t = threadIdx.x;
    if (b < 64){                 int i = b * 256 + t;         W1f[i] = ldany(W1, i, isf); }
    else if (b < 128){           int i = (b - 64) * 256 + t;  Wgf[i] = ldany(Wg, i, isf); }
    else if (b < 144){           int i = (b - 128) * 256 + t; W3f[i] = ldany(W3, i, isf); }
    else {
        int i = (b - 144) * 256 + t;     // 0..511
        float v;
        if      (i < 128) v = ldany(b1,  i,       isf);
        else if (i < 192) v = ldany(bg,  i - 128, isf);
        else if (i < 256) v = ldany(b3,  i - 192, isf);
        else if (i < 384) v = ldany(as_, i - 256, isf);
        else              v = ldany(ad_, i - 384, isf);
        vecf[i] = v;
    }
}

// ---------------- CSR build ----------------

__global__ void k_zero(int* p, int n){
    int i = blockIdx.x * blockDim.x + threadIdx.x;
    if (i < n) p[i] = 0;
}

static __device__ __forceinline__ int load_dst(const int* ei, int e, int is32){
    if (e >= E0) return e - E0;
    return is32 ? ei[E0 + e] : (int)((const long long*)ei)[E0 + e];
}
static __device__ __forceinline__ int load_src(const int* ei, int e, int is32){
    if (e >= E0) return e - E0;
    return is32 ? ei[e] : (int)((const long long*)ei)[e];
}

__global__ void k_count(const int* __restrict__ ei, const int* __restrict__ flag,
                        int* __restrict__ deg){
    int e = blockIdx.x * blockDim.x + threadIdx.x;
    if (e >= E_TOT) return;
    int is32 = flag[0];
    int dst = load_dst(ei, e, is32);
    int src = load_src(ei, e, is32);
    if ((unsigned)dst >= N_NODES || (unsigned)src >= N_NODES) return;
    atomicAdd(&deg[dst], 1);
}

__global__ void k_scanA(const int* __restrict__ deg, int* __restrict__ tmp, int* __restrict__ blk){
    __shared__ int s[256];
    int t = threadIdx.x;
    int i = blockIdx.x * 256 + t;
    int v = (i < N_NODES) ? deg[i] : 0;
    s[t] = v; __syncthreads();
    for (int off = 1; off < 256; off <<= 1){
        int x = (t >= off) ? s[t - off] : 0;
        __syncthreads();
        s[t] += x;
        __syncthreads();
    }
    if (t == 255) blk[blockIdx.x] = s[255];
    if (i < N_NODES) tmp[i] = s[t] - v;
}

__global__ void k_scanB(int* __restrict__ blk, int nb){
    __shared__ int s[256];
    int t = threadIdx.x;
    int v = (t < nb) ? blk[t] : 0;
    s[t] = v; __syncthreads();
    for (int off = 1; off < 256; off <<= 1){
        int x = (t >= off) ? s[t - off] : 0;
        __syncthreads();
        s[t] += x;
        __syncthreads();
    }
    if (t < nb) blk[t] = s[t] - v;
}

__global__ void k_scanC(int* __restrict__ row_ptr, const int* __restrict__ blk,
                        const int* __restrict__ deg, float* __restrict__ inv_sqrt){
    int i = blockIdx.x * blockDim.x + threadIdx.x;
    if (i < N_NODES){
        row_ptr[i] += blk[i >> 8];
        int d = deg[i];
        inv_sqrt[i] = (d > 0) ? rsqrtf((float)d) : 0.0f;
    }
    if (i == 0) row_ptr[N_NODES] = E_TOT;
}

__global__ void k_fill(const int* __restrict__ ei, const int* __restrict__ flag,
                       const int* __restrict__ row_ptr,
                       int* __restrict__ cursor, int* __restrict__ csr_src){
    int e = blockIdx.x * blockDim.x + threadIdx.x;
    if (e >= E_TOT) return;
    int is32 = flag[0];
    int dst = load_dst(ei, e, is32);
    int src = load_src(ei, e, is32);
    if ((unsigned)dst >= N_NODES || (unsigned)src >= N_NODES) return;
    int pos = row_ptr[dst] + atomicAdd(&cursor[dst], 1);
    csr_src[pos] = src;
}

// ---------------- gather of raw x (dual dtype), 128-dim ----------------
template<typename OT>
__global__ void k_aggx(const void* __restrict__ xv, const int* __restrict__ flag,
                       const int* __restrict__ rp, const int* __restrict__ csr,
                       const float* __restrict__ isq, OT* __restrict__ out){
    int n = blockIdx.x * 4 + (threadIdx.x >> 6);
    if (n >= N_NODES) return;
    int f = threadIdx.x & 63;
    float dn = isq[n], a0 = 0.f, a1 = 0.f;
    int b = rp[n], e = rp[n + 1];
    if (flag[1]){
        const float* x = (const float*)xv;
        for (int i = b; i < e; ++i){
            int s = csr[i];
            if ((unsigned)s >= N_NODES) continue;
            float c = dn * isq[s];
            a0 += c * x[(size_t)s * 128 + f];
            a1 += c * x[(size_t)s * 128 + f + 64];
        }
    } else {
        const bf16* x = (const bf16*)xv;
        for (int i = b; i < e; ++i){
            int s = csr[i];
            if ((unsigned)s >= N_NODES) continue;
            float c = dn * isq[s];
            a0 += c * __bfloat162float(x[(size_t)s * 128 + f]);
            a1 += c * __bfloat162float(x[(size_t)s * 128 + f + 64]);
        }
    }
    stf(&out[(size_t)n * 128 + f],      a0);
    stf(&out[(size_t)n * 128 + f + 64], a1);
}

// ---------------- dense GEMM (row-tiled, 4 rows/block), fp32 weights, in-place safe ----
template<int K, int M, typename IT, typename OT, bool RELU>
__global__ void k_gemm(const IT* __restrict__ A, const float* __restrict__ B,
                       const float* __restrict__ bias, OT* __restrict__ C, int nrows){
    __shared__ float as[4][K];
    int n0 = blockIdx.x * 4;
    int j  = threadIdx.x;            // blockDim.x == M
    #pragma unroll
    for (int r = 0; r < 4; ++r){
        int n = n0 + r;
        if (n < nrows && j < K) as[r][j] = ldf(&A[(size_t)n * K + j]);
    }
    __syncthreads();
    float acc[4] = {0.f, 0.f, 0.f, 0.f};
    for (int k = 0; k < K; ++k){
        float bv = B[k * M + j];
        #pragma unroll
        for (int r = 0; r < 4; ++r) acc[r] += as[r][k] * bv;
    }
    float bb = bias ? bias[j] : 0.f;
    #pragma unroll
    for (int r = 0; r < 4; ++r){
        int n = n0 + r;
        if (n < nrows){
            float v = acc[r] + bb;
            if (RELU) v = fmaxf(v, 0.f);
            stf(&C[(size_t)n * M + j], v);
        }
    }
}

// ---------------- GAT per-node attention logits (att in vecf[256..512)) ----------------
template<typename IT>
__global__ void k_att(const IT* __restrict__ H2, const float* __restrict__ vecf,
                      float* __restrict__ a_src, float* __restrict__ a_dst){
    int n = blockIdx.x;
    int h = threadIdx.x >> 6;
    int f = threadIdx.x & 63;
    float x  = ldf(H2 + (size_t)n * 128 + h * 64 + f);
    float ps = x * vecf[256 + h * 64 + f];
    float pd = x * vecf[384 + h * 64 + f];
    for (int off = 32; off; off >>= 1){
        ps += __shfl_down(ps, off, 64);
        pd += __shfl_down(pd, off, 64);
    }
    if (f == 0){
        a_src[n * 2 + h] = ps;
        a_dst[n * 2 + h] = pd;
    }
}

// ---------------- GAT aggregate (online softmax) + head-mean + bg + ELU ----------------
template<typename IT, typename OT>
__global__ void k_gat_agg(const IT* __restrict__ H2, const int* __restrict__ rp,
                          const int* __restrict__ csr, const float* __restrict__ a_src,
                          const float* __restrict__ a_dst, const float* __restrict__ vecf,
                          OT* __restrict__ out){
    int n = blockIdx.x * 4 + (threadIdx.x >> 6);
    if (n >= N_NODES) return;
    int f = threadIdx.x & 63;
    float ad0 = a_dst[n * 2], ad1 = a_dst[n * 2 + 1];
    float m0 = -INFINITY, m1 = -INFINITY;
    float l0 = 0.f, l1 = 0.f, o0 = 0.f, o1 = 0.f;
    int b = rp[n], e = rp[n + 1];
    for (int i = b; i < e; ++i){
        int s = csr[i];
        if ((unsigned)s >= N_NODES) continue;
        float e0 = a_src[s * 2] + ad0;
        float e1 = a_src[s * 2 + 1] + ad1;
        e0 = (e0 > 0.f) ? e0 : 0.2f * e0;   // leaky_relu 0.2
        e1 = (e1 > 0.f) ? e1 : 0.2f * e1;
        float nm0 = fmaxf(m0, e0), nm1 = fmaxf(m1, e1);
        float sc0 = __expf(m0 - nm0), sc1 = __expf(m1 - nm1);
        float p0  = __expf(e0 - nm0), p1  = __expf(e1 - nm1);
        const IT* hp = H2 + (size_t)s * 128;
        l0 = l0 * sc0 + p0;  o0 = o0 * sc0 + p0 * ldf(hp + f);
        l1 = l1 * sc1 + p1;  o1 = o1 * sc1 + p1 * ldf(hp + 64 + f);
        m0 = nm0; m1 = nm1;
    }
    float r0 = (l0 > 0.f) ? o0 / l0 : 0.f;
    float r1 = (l1 > 0.f) ? o1 / l1 : 0.f;
    float v = 0.5f * (r0 + r1) + vecf[128 + f];   // bg
    v = (v > 0.f) ? v : expm1f(v);                // ELU alpha=1
    stf(&out[(size_t)n * 64 + f], v);
}

// ---------------- GCN aggregate over 64-dim rows ----------------
template<typename IT>
__global__ void k_agg64(const IT* __restrict__ H, const int* __restrict__ rp,
                        const int* __restrict__ csr, const float* __restrict__ isq,
                        float* __restrict__ out){
    int n = blockIdx.x * 4 + (threadIdx.x >> 6);
    if (n >= N_NODES) return;
    int f = threadIdx.x & 63;
    float dn = isq[n], a = 0.f;
    int b = rp[n], e = rp[n + 1];
    for (int i = b; i < e; ++i){
        int s = csr[i];
        if ((unsigned)s >= N_NODES) continue;
        a += dn * isq[s] * ldf(H + (size_t)s * 64 + f);
    }
    out[(size_t)n * 64 + f] = a;
}

// ---------------- launch ----------------

extern "C" void kernel_launch(void* const* d_in, const int* in_sizes, int n_in,
                              void* d_out, int out_size, void* d_ws, size_t ws_size,
                              hipStream_t stream) {
    const void* x  = d_in[0];
    const int*  ei = (const int*)d_in[1];
    float* out = (float*)d_out;            // reference output dtype: float32

    char* p = (char*)d_ws;
    auto alloc = [&](size_t bytes) -> void* {
        void* r = (void*)p;
        p += (bytes + 255) & ~(size_t)255;
        return r;
    };
    int*   flag     = (int*)  alloc(8);
    int*   deg      = (int*)  alloc((size_t)N_NODES * 4);
    int*   cursor   = (int*)  alloc((size_t)N_NODES * 4);
    int*   row_ptr  = (int*)  alloc((size_t)(N_NODES + 1) * 4);
    int*   blk      = (int*)  alloc(256 * 4);
    int*   csr      = (int*)  alloc((size_t)E_TOT * 4);
    float* inv_sqrt = (float*)alloc((size_t)N_NODES * 4);
    float* a_src    = (float*)alloc((size_t)N_NODES * 2 * 4);
    float* a_dst    = (float*)alloc((size_t)N_NODES * 2 * 4);
    float* W1f      = (float*)alloc(16384 * 4);
    float* Wgf      = (float*)alloc(16384 * 4);
    float* W3f      = (float*)alloc(4096 * 4);
    float* vecf     = (float*)alloc(512 * 4);
    // big path (~44 MB): all-fp32 intermediates. small path (~25 MB): bf16.
    bool big = ws_size >= (size_t)48 * 1024 * 1024;
    void* bufY = alloc((size_t)N_NODES * 64  * (big ? 4 : 2));  // ELU output
    void* bufX = alloc((size_t)N_NODES * 128 * (big ? 4 : 2));  // h-chain
    float* aggE = (float*)bufX;   // fp32 (N,64), reuses bufX (dead by then; fits both paths)

    const int NB_NODE  = (N_NODES + 255) / 256;
    const int NB_EDGE  = (E_TOT + 255) / 256;
    const int NB_WAVE4 = (N_NODES + 3) / 4;

    // detect dtypes + convert weights to fp32
    k_detect<<<1, 256, 0, stream>>>(ei, (const unsigned*)x, flag);
    k_convert<<<146, 256, 0, stream>>>(flag, d_in[2], d_in[4], d_in[8],
                                       d_in[3], d_in[7], d_in[9], d_in[5], d_in[6],
                                       W1f, Wgf, W3f, vecf);

    // CSR build
    k_zero<<<NB_NODE, 256, 0, stream>>>(deg, N_NODES);
    k_zero<<<NB_NODE, 256, 0, stream>>>(cursor, N_NODES);
    k_count<<<NB_EDGE, 256, 0, stream>>>(ei, flag, deg);
    k_scanA<<<NB_NODE, 256, 0, stream>>>(deg, row_ptr, blk);
    k_scanB<<<1, 256, 0, stream>>>(blk, NB_NODE);
    k_scanC<<<NB_NODE, 256, 0, stream>>>(row_ptr, blk, deg, inv_sqrt);
    k_fill<<<NB_EDGE, 256, 0, stream>>>(ei, flag, row_ptr, cursor, csr);

    if (big){
        float* X = (float*)bufX;
        float* Y = (float*)bufY;
        // Layer 1 (commuted): X = A_hat x ; X = relu(X W1 + b1)  [in-place]
        k_aggx<float><<<NB_WAVE4, 256, 0, stream>>>(x, flag, row_ptr, csr, inv_sqrt, X);
        k_gemm<128, 128, float, float, true><<<NB_WAVE4, 128, 0, stream>>>(X, W1f, vecf, X, N_NODES);
        // Layer 2: X = X Wg  [in-place] ; attention ; online-softmax gather -> Y
        k_gemm<128, 128, float, float, false><<<NB_WAVE4, 128, 0, stream>>>(X, Wgf, nullptr, X, N_NODES);
        k_att<float><<<N_NODES, 128, 0, stream>>>(X, vecf, a_src, a_dst);
        k_gat_agg<float, float><<<NB_WAVE4, 256, 0, stream>>>(X, row_ptr, csr, a_src, a_dst, vecf, Y);
        // Layer 3 (commuted): aggE = A_hat Y ; out = aggE W3 + b3
        k_agg64<float><<<NB_WAVE4, 256, 0, stream>>>(Y, row_ptr, csr, inv_sqrt, aggE);
    } else {
        bf16* X = (bf16*)bufX;
        bf16* Y = (bf16*)bufY;
        k_aggx<bf16><<<NB_WAVE4, 256, 0, stream>>>(x, flag, row_ptr, csr, inv_sqrt, X);
        k_gemm<128, 128, bf16, bf16, true><<<NB_WAVE4, 128, 0, stream>>>(X, W1f, vecf, X, N_NODES);
        k_gemm<128, 128, bf16, bf16, false><<<NB_WAVE4, 128, 0, stream>>>(X, Wgf, nullptr, X, N_NODES);
        k_att<bf16><<<N_NODES, 128, 0, stream>>>(X, vecf, a_src, a_dst);
        k_gat_agg<bf16, bf16><<<NB_WAVE4, 256, 0, stream>>>(X, row_ptr, csr, a_src, a_dst, vecf, Y);
        k_agg64<bf16><<<NB_WAVE4, 256, 0, stream>>>(Y, row_ptr, csr, inv_sqrt, aggE);
    }
    k_gemm<64, 64, float, float, false><<<NB_WAVE4, 64, 0, stream>>>(aggE, W3f, vecf + 192, out, N_NODES);
}

// Round 6
// 528.641 us; speedup vs baseline: 1.5435x; 1.5435x over previous
//
#include <hip/hip_runtime.h>
#include <hip/hip_bf16.h>
#include <math.h>

#define N_NODES 50000
#define E0      800000
#define E_TOT   (E0 + N_NODES)

using bf16 = __hip_bfloat16;

// ---------------- dtype autodetect ----------------
// flag[0]=1 -> edges int32 ; flag[1]=1 -> float tensors are fp32
__global__ void k_detect(const int* __restrict__ ei, const unsigned* __restrict__ xu,
                         int* __restrict__ flag){
    __shared__ int e32, f32;
    if (threadIdx.x == 0){ e32 = 0; f32 = 0; }
    __syncthreads();
    if (ei[2 * threadIdx.x + 1] != 0) e32 = 1;        // int64 high words are 0
    if (threadIdx.x < 128){
        unsigned ex = (xu[threadIdx.x] >> 7) & 0xFF;  // bf16 exponent of low halfword
        if (ex < 100 || ex > 140) f32 = 1;            // fp32 mantissa bits look random
    }
    __syncthreads();
    if (threadIdx.x == 0){ flag[0] = e32; flag[1] = f32; }
}

static __device__ __forceinline__ float ldany(const void* p, int i, int isf32){
    return isf32 ? ((const float*)p)[i] : __bfloat162float(((const bf16*)p)[i]);
}

// vecf layout: b1 @0(128), bg @128(64), b3 @192(64), att_s @256(128), att_d @384(128)
__global__ void k_convert(const int* __restrict__ flag,
                          const void* W1, const void* Wg, const void* W3,
                          const void* b1, const void* bg, const void* b3,
                          const void* as_, const void* ad_,
                          float* __restrict__ W1f, float* __restrict__ Wgf,
                          float* __restrict__ W3f, float* __restrict__ vecf){
    int isf = flag[1];
    int b = blockIdx.x, t = threadIdx.x;
    if (b < 64){                 int i = b * 256 + t;         W1f[i] = ldany(W1, i, isf); }
    else if (b < 128){           int i = (b - 64) * 256 + t;  Wgf[i] = ldany(Wg, i, isf); }
    else if (b < 144){           int i = (b - 128) * 256 + t; W3f[i] = ldany(W3, i, isf); }
    else {
        int i = (b - 144) * 256 + t;     // 0..511
        float v;
        if      (i < 128) v = ldany(b1,  i,       isf);
        else if (i < 192) v = ldany(bg,  i - 128, isf);
        else if (i < 256) v = ldany(b3,  i - 192, isf);
        else if (i < 384) v = ldany(as_, i - 256, isf);
        else              v = ldany(ad_, i - 384, isf);
        vecf[i] = v;
    }
}

// x (N,128) -> bf16 copy (halves gather bytes in the mega1 kernel)
__global__ void k_convx(const void* __restrict__ xv, const int* __restrict__ flag,
                        bf16* __restrict__ xb){
    int i = blockIdx.x * 256 + threadIdx.x;
    if (i >= N_NODES * 128) return;
    xb[i] = __float2bfloat16(ldany(xv, i, flag[1]));
}

// ---------------- CSR build ----------------

__global__ void k_zero(int* p, int n){
    int i = blockIdx.x * blockDim.x + threadIdx.x;
    if (i < n) p[i] = 0;
}

static __device__ __forceinline__ int load_dst(const int* ei, int e, int is32){
    if (e >= E0) return e - E0;
    return is32 ? ei[E0 + e] : (int)((const long long*)ei)[E0 + e];
}
static __device__ __forceinline__ int load_src(const int* ei, int e, int is32){
    if (e >= E0) return e - E0;
    return is32 ? ei[e] : (int)((const long long*)ei)[e];
}

__global__ void k_count(const int* __restrict__ ei, const int* __restrict__ flag,
                        int* __restrict__ deg){
    int e = blockIdx.x * blockDim.x + threadIdx.x;
    if (e >= E_TOT) return;
    int is32 = flag[0];
    int dst = load_dst(ei, e, is32);
    int src = load_src(ei, e, is32);
    if ((unsigned)dst >= N_NODES || (unsigned)src >= N_NODES) return;
    atomicAdd(&deg[dst], 1);
}

__global__ void k_scanA(const int* __restrict__ deg, int* __restrict__ tmp, int* __restrict__ blk){
    __shared__ int s[256];
    int t = threadIdx.x;
    int i = blockIdx.x * 256 + t;
    int v = (i < N_NODES) ? deg[i] : 0;
    s[t] = v; __syncthreads();
    for (int off = 1; off < 256; off <<= 1){
        int x = (t >= off) ? s[t - off] : 0;
        __syncthreads();
        s[t] += x;
        __syncthreads();
    }
    if (t == 255) blk[blockIdx.x] = s[255];
    if (i < N_NODES) tmp[i] = s[t] - v;
}

__global__ void k_scanB(int* __restrict__ blk, int nb){
    __shared__ int s[256];
    int t = threadIdx.x;
    int v = (t < nb) ? blk[t] : 0;
    s[t] = v; __syncthreads();
    for (int off = 1; off < 256; off <<= 1){
        int x = (t >= off) ? s[t - off] : 0;
        __syncthreads();
        s[t] += x;
        __syncthreads();
    }
    if (t < nb) blk[t] = s[t] - v;
}

__global__ void k_scanC(int* __restrict__ row_ptr, const int* __restrict__ blk,
                        const int* __restrict__ deg, float* __restrict__ inv_sqrt){
    int i = blockIdx.x * blockDim.x + threadIdx.x;
    if (i < N_NODES){
        row_ptr[i] += blk[i >> 8];
        int d = deg[i];
        inv_sqrt[i] = (d > 0) ? rsqrtf((float)d) : 0.0f;
    }
    if (i == 0) row_ptr[N_NODES] = E_TOT;
}

__global__ void k_fill(const int* __restrict__ ei, const int* __restrict__ flag,
                       const int* __restrict__ row_ptr,
                       int* __restrict__ cursor, int* __restrict__ csr_src){
    int e = blockIdx.x * blockDim.x + threadIdx.x;
    if (e >= E_TOT) return;
    int is32 = flag[0];
    int dst = load_dst(ei, e, is32);
    int src = load_src(ei, e, is32);
    if ((unsigned)dst >= N_NODES || (unsigned)src >= N_NODES) return;
    int pos = row_ptr[dst] + atomicAdd(&cursor[dst], 1);
    csr_src[pos] = src;
}

// ---------------- mega1: gather(xb) -> GEMM1+ReLU -> GEMM2 -> att logits ----------------
// 128 threads/block, 4 nodes/block. Thread j owns feature column j.
__global__ __launch_bounds__(128) void k_mega1(
        const bf16* __restrict__ xb, const int* __restrict__ rp,
        const int* __restrict__ csr, const float* __restrict__ isq,
        const float* __restrict__ W1f, const float* __restrict__ Wgf,
        const float* __restrict__ vecf,
        bf16* __restrict__ X2, float* __restrict__ a_src, float* __restrict__ a_dst){
    __shared__ float as[4][128];
    __shared__ float hs[4][128];
    int n0 = blockIdx.x * 4;
    int j = threadIdx.x;

    // gather A_hat x rows for the block's 4 nodes (block-uniform edge loops)
    #pragma unroll
    for (int r = 0; r < 4; ++r){
        int n = n0 + r;
        float dn = isq[n], a = 0.f;
        int b = rp[n], e = rp[n + 1];
        for (int i = b; i < e; ++i){
            int s = csr[i];
            a += dn * isq[s] * __bfloat162float(xb[(size_t)s * 128 + j]);
        }
        as[r][j] = a;
    }
    __syncthreads();

    // GEMM1 + bias + ReLU  (h = relu(as @ W1 + b1))
    {
        float acc[4] = {0.f, 0.f, 0.f, 0.f};
        for (int k = 0; k < 128; ++k){
            float bv = W1f[k * 128 + j];
            #pragma unroll
            for (int r = 0; r < 4; ++r) acc[r] += as[r][k] * bv;
        }
        float bb = vecf[j];   // b1
        #pragma unroll
        for (int r = 0; r < 4; ++r) hs[r][j] = fmaxf(acc[r] + bb, 0.f);
    }
    __syncthreads();

    // GEMM2 (h2 = h @ Wg), att logits from fp32 registers, bf16 store
    float acc2[4] = {0.f, 0.f, 0.f, 0.f};
    for (int k = 0; k < 128; ++k){
        float bv = Wgf[k * 128 + j];
        #pragma unroll
        for (int r = 0; r < 4; ++r) acc2[r] += hs[r][k] * bv;
    }
    float asv = vecf[256 + j], adv = vecf[384 + j];  // att_src, att_dst (head-major)
    #pragma unroll
    for (int r = 0; r < 4; ++r){
        int n = n0 + r;
        X2[(size_t)n * 128 + j] = __float2bfloat16(acc2[r]);
        float ps = acc2[r] * asv, pd = acc2[r] * adv;
        for (int off = 32; off; off >>= 1){
            ps += __shfl_down(ps, off, 64);
            pd += __shfl_down(pd, off, 64);
        }
        if ((j & 63) == 0){
            int h = j >> 6;                      // wave 0 = head 0, wave 1 = head 1
            a_src[n * 2 + h] = ps;
            a_dst[n * 2 + h] = pd;
        }
    }
}

// ---------------- GAT aggregate: softmax (no-max; logits bounded) + mean + bg + ELU ----
__global__ __launch_bounds__(256) void k_gat(
        const bf16* __restrict__ X2, const int* __restrict__ rp,
        const int* __restrict__ csr, const float2* __restrict__ a_src,
        const float2* __restrict__ a_dst, const float* __restrict__ vecf,
        float* __restrict__ Y){
    int n = blockIdx.x * 4 + (threadIdx.x >> 6);
    int f = threadIdx.x & 63;
    float2 ad = a_dst[n];
    float l0 = 0.f, l1 = 0.f, o0 = 0.f, o1 = 0.f;
    int b = rp[n], e = rp[n + 1];
    for (int i = b; i < e; ++i){
        int s = csr[i];
        float2 av = a_src[s];
        float e0 = av.x + ad.x, e1 = av.y + ad.y;
        e0 = (e0 > 0.f) ? e0 : 0.2f * e0;       // leaky_relu 0.2
        e1 = (e1 > 0.f) ? e1 : 0.2f * e1;
        float p0 = __expf(e0), p1 = __expf(e1);
        const bf16* hp = X2 + (size_t)s * 128;
        l0 += p0;  o0 += p0 * __bfloat162float(hp[f]);
        l1 += p1;  o1 += p1 * __bfloat162float(hp[f + 64]);
    }
    float v = 0.5f * (o0 / l0 + o1 / l1) + vecf[128 + f];   // bg (l>0: self-loop)
    v = (v > 0.f) ? v : expm1f(v);                           // ELU alpha=1
    Y[(size_t)n * 64 + f] = v;
}

// ---------------- mega3: gather(Y) + W3 GEMM (W3 in LDS) -> out ----------------
__global__ __launch_bounds__(256) void k_mega3(
        const float* __restrict__ Y, const int* __restrict__ rp,
        const int* __restrict__ csr, const float* __restrict__ isq,
        const float* __restrict__ W3f, const float* __restrict__ vecf,
        float* __restrict__ out){
    __shared__ float w3s[4096];
    __shared__ float rows[4][64];
    for (int i = threadIdx.x; i < 4096; i += 256) w3s[i] = W3f[i];
    int w = threadIdx.x >> 6, f = threadIdx.x & 63;
    int n = blockIdx.x * 4 + w;
    float dn = isq[n], a = 0.f;
    int b = rp[n], e = rp[n + 1];
    for (int i = b; i < e; ++i){
        int s = csr[i];
        a += dn * isq[s] * Y[(size_t)s * 64 + f];
    }
    rows[w][f] = a;
    __syncthreads();
    float acc = vecf[192 + f];                  // b3
    for (int k = 0; k < 64; ++k) acc += rows[w][k] * w3s[k * 64 + f];
    out[(size_t)n * 64 + f] = acc;
}

// ---------------- launch ----------------

extern "C" void kernel_launch(void* const* d_in, const int* in_sizes, int n_in,
                              void* d_out, int out_size, void* d_ws, size_t ws_size,
                              hipStream_t stream) {
    const void* x  = d_in[0];
    const int*  ei = (const int*)d_in[1];
    float* out = (float*)d_out;

    char* p = (char*)d_ws;
    auto alloc = [&](size_t bytes) -> void* {
        void* r = (void*)p;
        p += (bytes + 255) & ~(size_t)255;
        return r;
    };
    int*   flag     = (int*)  alloc(8);
    int*   deg      = (int*)  alloc((size_t)N_NODES * 4);
    int*   cursor   = (int*)  alloc((size_t)N_NODES * 4);
    int*   row_ptr  = (int*)  alloc((size_t)(N_NODES + 1) * 4);
    int*   blk      = (int*)  alloc(256 * 4);
    int*   csr      = (int*)  alloc((size_t)E_TOT * 4);
    float* inv_sqrt = (float*)alloc((size_t)N_NODES * 4);
    float* a_src    = (float*)alloc((size_t)N_NODES * 2 * 4);
    float* a_dst    = (float*)alloc((size_t)N_NODES * 2 * 4);
    float* W1f      = (float*)alloc(16384 * 4);
    float* Wgf      = (float*)alloc(16384 * 4);
    float* W3f      = (float*)alloc(4096 * 4);
    float* vecf     = (float*)alloc(512 * 4);
    bf16*  xb       = (bf16*) alloc((size_t)N_NODES * 128 * 2);  // 12.8 MB
    bf16*  X2       = (bf16*) alloc((size_t)N_NODES * 128 * 2);  // 12.8 MB
    float* Y        = (float*)alloc((size_t)N_NODES * 64 * 4);   // 12.8 MB
    // total ~43.6 MB

    const int NB_NODE = (N_NODES + 255) / 256;
    const int NB_EDGE = (E_TOT + 255) / 256;
    const int NB4     = N_NODES / 4;     // 12500, exact

    k_detect<<<1, 256, 0, stream>>>(ei, (const unsigned*)x, flag);
    k_convert<<<146, 256, 0, stream>>>(flag, d_in[2], d_in[4], d_in[8],
                                       d_in[3], d_in[7], d_in[9], d_in[5], d_in[6],
                                       W1f, Wgf, W3f, vecf);
    k_convx<<<(N_NODES * 128 + 255) / 256, 256, 0, stream>>>(x, flag, xb);

    k_zero<<<NB_NODE, 256, 0, stream>>>(deg, N_NODES);
    k_zero<<<NB_NODE, 256, 0, stream>>>(cursor, N_NODES);
    k_count<<<NB_EDGE, 256, 0, stream>>>(ei, flag, deg);
    k_scanA<<<NB_NODE, 256, 0, stream>>>(deg, row_ptr, blk);
    k_scanB<<<1, 256, 0, stream>>>(blk, NB_NODE);
    k_scanC<<<NB_NODE, 256, 0, stream>>>(row_ptr, blk, deg, inv_sqrt);
    k_fill<<<NB_EDGE, 256, 0, stream>>>(ei, flag, row_ptr, cursor, csr);

    k_mega1<<<NB4, 128, 0, stream>>>(xb, row_ptr, csr, inv_sqrt, W1f, Wgf, vecf,
                                     X2, a_src, a_dst);
    k_gat<<<NB4, 256, 0, stream>>>(X2, row_ptr, csr, (const float2*)a_src,
                                   (const float2*)a_dst, vecf, Y);
    k_mega3<<<NB4, 256, 0, stream>>>(Y, row_ptr, csr, inv_sqrt, W3f, vecf, out);
}